// Round 8
// baseline (396.006 us; speedup 1.0000x reference)
//
#include <hip/hip_runtime.h>

// Gaussian blur (theta=3, truncate=4 -> r=12, 25 taps), separable, minus identity.
// src: (4, 512, 512, 21) fp32 NHWC.  out = H(V(src)) - src with zero padding.
// SINGLE streaming kernel (H-conv then V-conv, mathematically identical):
//   block = 32w x 21c column tile x 64-row stripe, 336 threads, streams 88 rows.
//   Per step: stage src row slice (LDS dbuf, w-halo read across tile edges),
//   H-conv (26-tap from LDS, 2 outputs/thread) -> h-row LDS dbuf, ONE barrier,
//   V-accumulate into a ring of 25 register partials per column (2 cols/thread,
//   50 VGPRs). Ring slots are compile-time: steps processed in 25-blocks via
//   25 expanded STEP macros; first tap OVERWRITES the slot (kills aliasing).
//   Completed rows: coalesced float2 store of (ring - src), src row L2-hot.
// No intermediate buffer, no fp16: HBM = src ~1.375x + out once (~210 MB).
// LDS 14.8 KB, target 2 blocks/CU via __launch_bounds__(336,3) (VGPR cap 128).

#define BATCH 4
#define HH 512
#define WW 512
#define CC 21
#define WC (WW * CC)            // 10752 floats per row
#define IMG ((size_t)HH * WC)   // elems per batch image
#define RAD 12

// g(d) = exp(-d^2/18), index = d + 12 (symmetric)
__device__ static constexpr float GW[25] = {
    3.3546263e-04f, 1.2038700e-03f, 3.8659300e-03f, 1.1108997e-02f, 2.8565500e-02f,
    6.5728500e-02f, 1.3533528e-01f, 2.4935221e-01f, 4.1111229e-01f, 6.0653066e-01f,
    8.0073740e-01f, 9.4595947e-01f, 1.0000000e+00f, 9.4595947e-01f, 8.0073740e-01f,
    6.0653066e-01f, 4.1111229e-01f, 2.4935221e-01f, 1.3533528e-01f, 6.5728500e-02f,
    2.8565500e-02f, 1.1108997e-02f, 3.8659300e-03f, 1.2038700e-03f, 3.3546263e-04f
};

constexpr int NT    = 336;                 // threads: 16 w-groups x 21 channels
constexpr int SH    = 64;                  // output rows per stripe
constexpr int NSTEP = SH + 2 * RAD;        // 88 streamed rows
constexpr int CT    = 672;                 // flat cols per tile (32 w x 21 c)
constexpr int SLICE = CT + 2 * RAD * CC;   // 1176 staged floats (w-halo +-12)
constexpr int NWT   = WC / CT;             // 16 w-tiles
constexpr int NST   = HH / SH;             // 8 stripes
constexpr int NWG   = NWT * NST * BATCH;   // 512 blocks (%8==0, bijective swizzle)

// One streamed step. O is a compile-time literal 0..24; st = base + O.
// Uniform guards throughout (st, grh block-uniform) -> barriers legal.
#define STEP(O) do {                                                          \
    const int st = base + (O);                                                \
    if (st < NSTEP) {                                                         \
        const int grh = row0 + st - RAD;      /* global src row for H */      \
        { /* ---- stage NEXT row into sb[(st+1)&1] (float2) ---- */           \
            const int grs = grh + 1;                                          \
            if ((unsigned)grs < HH) {                                         \
                const float* srow = sbase + (size_t)grs * WC;                 \
                _Pragma("unroll")                                             \
                for (int m = 0; m < 2; ++m) {                                 \
                    const int i2 = tid + m * NT;                              \
                    if (i2 < SLICE / 2) {                                     \
                        const int gf = wt672 - RAD * CC + 2 * i2;             \
                        float2 vv = make_float2(0.f, 0.f);                    \
                        if ((unsigned)gf < WC)                                \
                            vv = *(const float2*)(srow + gf);                 \
                        *(float2*)&sb[(st + 1) & 1][2 * i2] = vv;             \
                    }                                                         \
                }                                                             \
            }                                                                 \
        }                                                                     \
        if ((unsigned)grh < HH) {  /* ---- H-conv from sb[st&1] ---- */       \
            const float* sbc = &sb[st & 1][ib];                               \
            float h0 = 0.f, h1 = 0.f;                                         \
            float xp = sbc[0];                                                \
            _Pragma("unroll")                                                 \
            for (int k = 0; k < 25; ++k) {                                    \
                const float xn = sbc[(k + 1) * CC];                           \
                h0 = fmaf(GW[k], xp, h0);                                     \
                h1 = fmaf(GW[k], xn, h1);                                     \
                xp = xn;                                                      \
            }                                                                 \
            hb[st & 1][ib]      = h0;                                         \
            hb[st & 1][ib + CC] = h1;                                         \
        }                                                                     \
        __syncthreads();                                                      \
        if ((unsigned)grh < HH) {  /* ---- V ring accumulate ---- */          \
            const float2 hv = *(const float2*)&hb[st & 1][2 * tid];           \
            _Pragma("unroll")                                                 \
            for (int q = 0; q < 25; ++q) {                                    \
                const float w = GW[(((O) - q) + 25) % 25];                    \
                if (q == (O)) {        /* first tap: OVERWRITE slot */        \
                    r0[q] = GW[0] * hv.x;                                     \
                    r1[q] = GW[0] * hv.y;                                     \
                } else {                                                      \
                    r0[q] = fmaf(w, hv.x, r0[q]);                             \
                    r1[q] = fmaf(w, hv.y, r1[q]);                             \
                }                                                             \
            }                                                                 \
        }                                                                     \
        if (st >= 24) {            /* ---- completed output row ---- */       \
            constexpr int qd = ((O) + 1) % 25;                                \
            const int gro = row0 + st - 24;                                   \
            const size_t ob = ((size_t)b * HH + gro) * WC + wt672 + 2 * tid;  \
            const float2 sv = *(const float2*)(src + ob);                     \
            float2 ov;                                                        \
            ov.x = r0[qd] - sv.x;                                             \
            ov.y = r1[qd] - sv.y;                                             \
            *(float2*)(out + ob) = ov;                                        \
        }                                                                     \
    }                                                                         \
} while (0)

__global__ __launch_bounds__(NT, 3)
void gauss_stream_kernel(const float* __restrict__ src, float* __restrict__ out)
{
    __shared__ float sb[2][SLICE];   // 9408 B: src row slices (dbuf)
    __shared__ float hb[2][CT];      // 5376 B: h-conv rows (dbuf)

    const int tid = threadIdx.x;

    // XCD-chunked bijective swizzle: each XCD owns 64 consecutive work items
    // = 4 vertically adjacent stripes x 16 w-tiles of one batch (halo L2-shared).
    const int bid = blockIdx.x;
    const int g   = (bid & 7) * (NWG / 8) + (bid >> 3);
    const int b   = g >> 7;                  // batch
    const int rem = g & 127;
    const int row0  = (rem >> 4) * SH;       // stripe start row
    const int wt672 = (rem & 15) * CT;       // tile start flat col
    const float* sbase = src + (size_t)b * IMG;

    const int c  = tid % CC;                 // channel
    const int wg = tid / CC;                 // w-group 0..15 (2 w's each)
    const int ib = wg * 42 + c;              // slice idx of w_local=2wg-12 tap

    float r0[25], r1[25];                    // V ring: 25 partials x 2 cols
#pragma unroll
    for (int q = 0; q < 25; ++q) { r0[q] = 0.f; r1[q] = 0.f; }

    // prologue: stage row (row0-12) into sb[0] for step 0
    {
        const int grow = row0 - RAD;
        if ((unsigned)grow < HH) {
            const float* srow = sbase + (size_t)grow * WC;
#pragma unroll
            for (int m = 0; m < 2; ++m) {
                const int i2 = tid + m * NT;
                if (i2 < SLICE / 2) {
                    const int gf = wt672 - RAD * CC + 2 * i2;
                    float2 vv = make_float2(0.f, 0.f);
                    if ((unsigned)gf < WC)
                        vv = *(const float2*)(srow + gf);
                    *(float2*)&sb[0][2 * i2] = vv;
                }
            }
        }
    }
    __syncthreads();

    // main loop: 25-step blocks (base % 25 == 0 -> ring slots compile-time)
#pragma unroll 1
    for (int base = 0; base < NSTEP; base += 25) {
        STEP(0);  STEP(1);  STEP(2);  STEP(3);  STEP(4);
        STEP(5);  STEP(6);  STEP(7);  STEP(8);  STEP(9);
        STEP(10); STEP(11); STEP(12); STEP(13); STEP(14);
        STEP(15); STEP(16); STEP(17); STEP(18); STEP(19);
        STEP(20); STEP(21); STEP(22); STEP(23); STEP(24);
    }
}

extern "C" void kernel_launch(void* const* d_in, const int* in_sizes, int n_in,
                              void* d_out, int out_size, void* d_ws, size_t ws_size,
                              hipStream_t stream)
{
    const float* src = (const float*)d_in[0];
    float*       out = (float*)d_out;
    (void)d_ws; (void)ws_size;

    gauss_stream_kernel<<<dim3(NWG), NT, 0, stream>>>(src, out);
}